// Round 12
// baseline (3220.698 us; speedup 1.0000x reference)
//
#include <hip/hip_runtime.h>
#include <math.h>

#define BN 2048
#define DN 8
#define NEGW -1e9f
#define TPB 256            // threads per block (4 waves)
#define RPB 128            // rows per block (each thread owns 8 rows)
#define RS 16              // row-slots (t & 15); rows rs + 16*r, r=0..7
#define JSPLIT 16          // j-chunks; jc = t>>4
#define SLOTS (BN/2)       // 1024 logical float4 slots (2 j per slot)
#define SPC (SLOTS/JSPLIT) // 64 slots = 128 j per chunk
#define CPAD 65            // physical chunk stride in slots (+1 pad)
#define NBLK (DN*4*16)     // 512 blocks = 2/CU, all co-resident
#define NGRP 8
#define GSZ (NBLK/NGRP)    // 64
#define NEPS 51
#define NITER (NEPS+2)     // 53 phases

typedef float f2 __attribute__((ext_vector_type(2)));

static __device__ __forceinline__ float wave_reduce_sum(float v){
  #pragma unroll
  for (int off = 32; off > 0; off >>= 1) v += __shfl_xor(v, off, 64);
  return v;
}
static __device__ __forceinline__ f2 exp2_hw(f2 e){
  return (f2){__builtin_amdgcn_exp2f(e.x), __builtin_amdgcn_exp2f(e.y)};
}

// Device-scope tree grid barrier. Safe because all NBLK blocks are
// co-resident (2 blocks/CU: 42KB LDS, 256 thr, ~80 VGPR << limits).
// bar[g*16] g=0..7 group counters; bar[128] root; bar[144] generation.
// Generation compare uses '<' so late spinners can never miss a release.
static __device__ __forceinline__ void grid_barrier(unsigned* bar, unsigned target){
  __syncthreads();
  if (threadIdx.x == 0){
    __threadfence();   // make this block's global writes agent-visible
    int grp = blockIdx.x & (NGRP-1);
    unsigned a = __hip_atomic_fetch_add(&bar[grp*16], 1u, __ATOMIC_ACQ_REL, __HIP_MEMORY_SCOPE_AGENT);
    if (a == GSZ-1){
      __hip_atomic_store(&bar[grp*16], 0u, __ATOMIC_RELAXED, __HIP_MEMORY_SCOPE_AGENT);
      unsigned r = __hip_atomic_fetch_add(&bar[128], 1u, __ATOMIC_ACQ_REL, __HIP_MEMORY_SCOPE_AGENT);
      if (r == NGRP-1){
        __hip_atomic_store(&bar[128], 0u, __ATOMIC_RELAXED, __HIP_MEMORY_SCOPE_AGENT);
        __hip_atomic_store(&bar[144], target, __ATOMIC_RELEASE, __HIP_MEMORY_SCOPE_AGENT);
      }
    }
    while (__hip_atomic_load(&bar[144], __ATOMIC_ACQUIRE, __HIP_MEMORY_SCOPE_AGENT) < target){
      __builtin_amdgcn_s_sleep(8);
    }
    __threadfence();   // belt & suspenders: pull remote writes
  }
  __syncthreads();
}

// Transpose inputs into per-dim columns, build masked y, counts, logw.
__global__ void setup_kernel(const float* __restrict__ pred, const float* __restrict__ targ,
                             float* __restrict__ xcol, float* __restrict__ ycol,
                             float* __restrict__ logw, float* __restrict__ counts){
  int d = blockIdx.x;          // 8 blocks
  int t = threadIdx.x;         // 256 threads
  int lane = t & 63, wave = t >> 6;
  float mk[BN/256];
  float c = 0.f;
  for (int k = 0; k < BN/256; k++){
    int i = t + k*256;
    float tv = targ[i*DN + d];
    bool m = !(tv != tv);      // !isnan
    mk[k] = m ? 1.f : 0.f;
    c += mk[k];
    ycol[d*BN + i] = m ? tv : 0.f;
    xcol[d*BN + i] = pred[i*DN + d];
  }
  __shared__ float sh[4];
  __shared__ float logn_sh;
  float cw = wave_reduce_sum(c);
  if (lane == 0) sh[wave] = cw;
  __syncthreads();
  if (t == 0){
    float tot = sh[0] + sh[1] + sh[2] + sh[3];
    counts[d] = tot;
    logn_sh = logf(fmaxf(tot, 1.f));
  }
  __syncthreads();
  float ln = logn_sh;
  for (int k = 0; k < BN/256; k++){
    int i = t + k*256;
    logw[d*BN + i] = (mk[k] > 0.f) ? -ln : NEGW;
  }
}

// Round-12: PERSISTENT kernel — all 53 Sinkhorn phases in one launch with a
// tree grid-barrier between phases. r11 post-mortem: compute floor ~5.5us/
// step but wall 19.4us incl. launch/ramp/drain convoy paid 53x. Persistent
// form removes 52 launch+drain cycles and hoists loop invariants: y staged
// to LDS once, row xi / logw in registers once, per-step stage = 2 float4
// H loads/thread. Compute core / merge / epilogue verbatim r11 (absmax 0.0).
__global__ __launch_bounds__(TPB) void sink_all(
      const float* __restrict__ xcol, const float* __restrict__ ycol,
      const float* __restrict__ logw,
      float* __restrict__ dual0, float* __restrict__ dual1,
      float* __restrict__ Hb0, float* __restrict__ Hb1,
      unsigned* __restrict__ bar){
  const float L2E = 1.44269504088896340736f;
  const float LN2 = 0.69314718055994530942f;
  __shared__ float4 pair4[JSPLIT*CPAD];   // 16.25 KB planar: (y0,y1,h2_0,h2_1)
  __shared__ float2 ysl[JSPLIT*CPAD];     // 8.3 KB: persistent y pairs
  __shared__ float2 pms[JSPLIT][RPB];     // 16 KB: per-chunk (max, sum)
  __shared__ float s_el[NEPS];
  __shared__ float s_eps[NITER], s_ie[NITER], s_ien[NITER];
  __shared__ int   s_mode[NITER];

  int bid = blockIdx.x;
  int rc  = bid & 15;          // 16 row-chunks of 128 rows
  int mat = (bid >> 4) & 3;    // 0:f 1:g 2:a 3:b
  int d   = bid >> 6;          // dim
  int t   = threadIdx.x;
  int rs  = t & (RS-1);        // row-slot
  int jc  = t >> 4;            // j-chunk 0..15

  // eps schedule (matches geomloss; same f64 formula as reference)
  if (t == 0){
    double ls = 2.0*log(8.0), st = 2.0*log(0.9);
    s_el[0] = 64.0f;
    for (int k = 0; k < NEPS-2; k++) s_el[1+k] = (float)exp(ls + st*(double)k);
    s_el[NEPS-1] = 0.05f*0.05f;
    for (int j = 0; j < NITER; j++){
      int idx = (j == 0) ? 0 : ((j <= NEPS) ? j-1 : NEPS-1);
      int nid = (j == 0) ? 0 : ((j < NEPS) ? j : NEPS-1);
      s_eps[j]  = s_el[idx];
      s_ie[j]   = 1.0f/s_el[idx];
      s_ien[j]  = 1.0f/s_el[nid];
      s_mode[j] = (j == 0) ? 0 : ((j <= NEPS) ? 1 : 2);
    }
  }

  const float* xb = xcol + d*BN;
  const float* yb = ycol + d*BN;
  const float* lw = logw + d*BN;
  const float* ri; const float* pj; int hsel;
  switch (mat){
    case 0:  ri = xb; pj = yb; hsel = 1; break;  // ft: rows x, pts y, dual g
    case 1:  ri = yb; pj = xb; hsel = 0; break;  // gt: rows y, pts x, dual f
    case 2:  ri = xb; pj = xb; hsel = 2; break;  // at
    default: ri = yb; pj = yb; hsel = 3; break;  // bt
  }
  size_t moff = (size_t)mat *DN*BN + d*BN;
  size_t hoff = (size_t)hsel*DN*BN + d*BN;

  // stage y pairs into LDS ONCE (same slot mapping as pair4)
  const float2* pj2 = (const float2*)pj;
  #pragma unroll
  for (int k = 0; k < SLOTS/TPB; k++){
    int idx = t + k*TPB;
    ysl[idx + (idx>>6)] = pj2[idx];
  }

  // persistent per-thread row data
  int row0 = rc*RPB + rs;
  float xi[8];
  #pragma unroll
  for (int r = 0; r < 8; r++) xi[r] = ri[row0 + RS*r];
  int rowe = rc*RPB + t;
  float xe = 0.f, lwrow = 0.f;
  if (t < RPB){ xe = ri[rowe]; lwrow = lw[rowe]; }
  __syncthreads();   // tables + ysl ready

  #pragma unroll 1
  for (int j = 0; j < NITER; j++){
    int wp = j & 1, rp = wp ^ 1;           // j=0 writes parity 0
    int mode  = s_mode[j];
    float eps = s_eps[j], inv_eps = s_ie[j], ien = s_ien[j];
    const float c1 = L2E * inv_eps;
    const float c2 = 0.5f * inv_eps * L2E;

    const float* Hrd = (j == 0) ? lw : (((rp == 0) ? Hb0 : Hb1) + hoff);
    const float* dmp = ((rp == 0) ? dual0 : dual1) + moff;
    float*       op  = ((wp == 0) ? dual0 : dual1) + moff;
    float*       oh  = ((wp == 0) ? Hb0 : Hb1) + moff;

    // ---- stage h2 into pair4: slots 4t..4t+3, two float4 H loads ----
    {
      const float4* H4 = (const float4*)Hrd;
      float4 ha = H4[2*t];
      float4 hb = H4[2*t+1];
      int i0 = 4*t;
      int p0 = i0 + (i0 >> 6);             // 4 slots stay in one pad-group
      float2 y0 = ysl[p0+0], y1 = ysl[p0+1], y2 = ysl[p0+2], y3 = ysl[p0+3];
      pair4[p0+0] = make_float4(y0.x, y0.y, fmaf(-c2*y0.x, y0.x, L2E*ha.x), fmaf(-c2*y0.y, y0.y, L2E*ha.y));
      pair4[p0+1] = make_float4(y1.x, y1.y, fmaf(-c2*y1.x, y1.x, L2E*ha.z), fmaf(-c2*y1.y, y1.y, L2E*ha.w));
      pair4[p0+2] = make_float4(y2.x, y2.y, fmaf(-c2*y2.x, y2.x, L2E*hb.x), fmaf(-c2*y2.y, y2.y, L2E*hb.y));
      pair4[p0+3] = make_float4(y3.x, y3.y, fmaf(-c2*y3.x, y3.x, L2E*hb.z), fmaf(-c2*y3.y, y3.y, L2E*hb.w));
    }
    f2 a2[8];
    #pragma unroll
    for (int r = 0; r < 8; r++){ float al = c1 * xi[r]; a2[r] = (f2){al, al}; }
    __syncthreads();

    // ---- single sweep: online max + exp-sum, 8-slot read batches ----
    const float4* cb = pair4 + jc*CPAD;
    float mrow[8];
    f2 sA[8], sB[8];
    #pragma unroll
    for (int r = 0; r < 8; r++){
      mrow[r] = -INFINITY;
      sA[r] = (f2){0.f, 0.f};
      sB[r] = (f2){0.f, 0.f};
    }
    #pragma unroll 1
    for (int q = 0; q < SPC; q += 8){
      float4 P0 = cb[q+0]; float4 P1 = cb[q+1];
      float4 P2 = cb[q+2]; float4 P3 = cb[q+3];
      float4 P4 = cb[q+4]; float4 P5 = cb[q+5];
      float4 P6 = cb[q+6]; float4 P7 = cb[q+7];
      #pragma unroll
      for (int r = 0; r < 8; r++){
        f2 a = a2[r];
        f2 v0 = __builtin_elementwise_fma(a, (f2){P0.x,P0.y}, (f2){P0.z,P0.w});
        f2 v1 = __builtin_elementwise_fma(a, (f2){P1.x,P1.y}, (f2){P1.z,P1.w});
        f2 v2 = __builtin_elementwise_fma(a, (f2){P2.x,P2.y}, (f2){P2.z,P2.w});
        f2 v3 = __builtin_elementwise_fma(a, (f2){P3.x,P3.y}, (f2){P3.z,P3.w});
        f2 v4 = __builtin_elementwise_fma(a, (f2){P4.x,P4.y}, (f2){P4.z,P4.w});
        f2 v5 = __builtin_elementwise_fma(a, (f2){P5.x,P5.y}, (f2){P5.z,P5.w});
        f2 v6 = __builtin_elementwise_fma(a, (f2){P6.x,P6.y}, (f2){P6.z,P6.w});
        f2 v7 = __builtin_elementwise_fma(a, (f2){P7.x,P7.y}, (f2){P7.z,P7.w});
        f2 t0 = __builtin_elementwise_max(v0, v1);
        f2 t1 = __builtin_elementwise_max(v2, v3);
        f2 t2 = __builtin_elementwise_max(v4, v5);
        f2 t3 = __builtin_elementwise_max(v6, v7);
        f2 u0 = __builtin_elementwise_max(t0, t1);
        f2 u1 = __builtin_elementwise_max(t2, t3);
        f2 w  = __builtin_elementwise_max(u0, u1);
        float bm = fmaxf(w.x, w.y);
        float mo = mrow[r];
        float mn = fmaxf(mo, bm);
        float sc = __builtin_amdgcn_exp2f(mo - mn);   // first batch: exp2(-inf)=0
        mrow[r] = mn;
        f2 scv = (f2){sc, sc};
        f2 mv  = (f2){mn, mn};
        f2 x0 = exp2_hw(v0 - mv);
        f2 x1 = exp2_hw(v1 - mv);
        f2 x2 = exp2_hw(v2 - mv);
        f2 x3 = exp2_hw(v3 - mv);
        f2 x4 = exp2_hw(v4 - mv);
        f2 x5 = exp2_hw(v5 - mv);
        f2 x6 = exp2_hw(v6 - mv);
        f2 x7 = exp2_hw(v7 - mv);
        sA[r] = __builtin_elementwise_fma(sA[r], scv, x0);
        sB[r] = __builtin_elementwise_fma(sB[r], scv, x1);
        sA[r] += x2;  sB[r] += x3;
        sA[r] += x4;  sB[r] += x5;
        sA[r] += x6;  sB[r] += x7;
      }
    }
    #pragma unroll
    for (int r = 0; r < 8; r++){
      f2 s = sA[r] + sB[r];
      pms[jc][rs + RS*r] = make_float2(mrow[r], s.x + s.y);
    }
    __syncthreads();

    // ---- cross-chunk merge + epilogue ----
    if (t < RPB){
      float M = -INFINITY;
      #pragma unroll
      for (int k = 0; k < JSPLIT; k++) M = fmaxf(M, pms[k][t].x);
      float s = 0.f;
      #pragma unroll
      for (int k = 0; k < JSPLIT; k++){
        float2 p = pms[k][t];
        s = fmaf(p.y, __builtin_amdgcn_exp2f(p.x - M), s);
      }
      float beta = c2 * xe * xe;
      float lse2 = (M + __builtin_amdgcn_logf(s)) - beta;   // log2-domain LSE
      float tn = -eps * (LN2 * lse2);
      float outv;
      if (mode == 1 || (mode == 2 && mat >= 2)) outv = 0.5f * (dmp[rowe] + tn);
      else                                      outv = tn;
      op[rowe] = outv;
      oh[rowe] = fmaf(outv, ien, lwrow);  // prefused h for next phase
    }
    if (j < NITER-1) grid_barrier(bar, (unsigned)(j+1));
  }
}

__global__ void reduce_kernel(const float* __restrict__ dual, const float* __restrict__ logw,
                              const float* __restrict__ counts, float* __restrict__ out){
  int d = blockIdx.x;
  int t = threadIdx.x;
  int lane = t & 63, wave = t >> 6;
  float acc = 0.f;
  for (int k = 0; k < BN/256; k++){
    int i = t + k*256;
    float w  = expf(logw[d*BN + i]);   // exp(-1e9) -> 0, else 1/n
    float fv = dual[0*DN*BN + d*BN + i];
    float gv = dual[1*DN*BN + d*BN + i];
    float av = dual[2*DN*BN + d*BN + i];
    float bv = dual[3*DN*BN + d*BN + i];
    acc += w * ((fv - av) + (gv - bv));
  }
  __shared__ float sh[4];
  float aw = wave_reduce_sum(acc);
  if (lane == 0) sh[wave] = aw;
  __syncthreads();
  if (t == 0){
    float tot = sh[0] + sh[1] + sh[2] + sh[3];
    out[1 + d] = (counts[d] > 1.5f) ? tot : 0.f;
  }
}

__global__ void total_kernel(float* __restrict__ out){
  if (threadIdx.x == 0 && blockIdx.x == 0){
    float s = 0.f;
    for (int d = 0; d < DN; d++) s += out[1 + d];
    out[0] = s / (float)DN;
  }
}

extern "C" void kernel_launch(void* const* d_in, const int* in_sizes, int n_in,
                              void* d_out, int out_size, void* d_ws, size_t ws_size,
                              hipStream_t stream){
  const float* pred = (const float*)d_in[0];
  const float* targ = (const float*)d_in[1];
  float* out = (float*)d_out;
  float* ws  = (float*)d_ws;

  float* xcol   = ws;                                   // 16384
  float* ycol   = ws + (size_t)DN*BN;                   // 16384
  float* logw   = ws + (size_t)2*DN*BN;                 // 16384
  float* counts = ws + (size_t)3*DN*BN;                 // 64
  float* buf0   = ws + (size_t)3*DN*BN + 64;            // 65536
  float* buf1   = buf0 + (size_t)4*DN*BN;               // 65536
  float* H0     = buf1 + (size_t)4*DN*BN;               // 65536
  float* H1     = H0   + (size_t)4*DN*BN;               // 65536
  unsigned* bar = (unsigned*)(H1 + (size_t)4*DN*BN);    // 64B-aligned

  hipMemsetAsync(bar, 0, 12*16*sizeof(unsigned), stream);
  setup_kernel<<<DN, 256, 0, stream>>>(pred, targ, xcol, ycol, logw, counts);
  sink_all<<<NBLK, TPB, 0, stream>>>(xcol, ycol, logw, buf0, buf1, H0, H1, bar);
  // NITER = 53 phases; final phase index 52 writes parity 0 -> buf0
  reduce_kernel<<<DN, 256, 0, stream>>>(buf0, logw, counts, out);
  total_kernel<<<1, 64, 0, stream>>>(out);
}

// Round 13
// 1041.931 us; speedup vs baseline: 3.0911x; 3.0911x over previous
//
#include <hip/hip_runtime.h>
#include <math.h>

#define BN 2048
#define DN 8
#define NEGW -1e9f
#define TPB 256            // threads per block (4 waves)
#define RPB 128            // rows per block (each thread owns 8 rows)
#define RS 16              // row-slots (t & 15); rows rs + 16*r, r=0..7
#define JSPLIT 16          // j-chunks; jc = t>>4 (quarter-wave uniform broadcast)
#define SLOTS (BN/2)       // logical float4 slots (2 j per slot)
#define SPC (SLOTS/JSPLIT) // 64 slots = 128 j per chunk
#define CPAD 65            // physical chunk stride in slots (+1 pad)

typedef float f2 __attribute__((ext_vector_type(2)));

static __device__ __forceinline__ float wave_reduce_sum(float v){
  #pragma unroll
  for (int off = 32; off > 0; off >>= 1) v += __shfl_xor(v, off, 64);
  return v;
}
static __device__ __forceinline__ f2 exp2_hw(f2 e){
  return (f2){__builtin_amdgcn_exp2f(e.x), __builtin_amdgcn_exp2f(e.y)};
}

// Transpose inputs into per-dim columns, build masked y, counts, logw.
__global__ void setup_kernel(const float* __restrict__ pred, const float* __restrict__ targ,
                             float* __restrict__ xcol, float* __restrict__ ycol,
                             float* __restrict__ logw, float* __restrict__ counts){
  int d = blockIdx.x;          // 8 blocks
  int t = threadIdx.x;         // 256 threads
  int lane = t & 63, wave = t >> 6;
  float mk[BN/256];
  float c = 0.f;
  for (int k = 0; k < BN/256; k++){
    int i = t + k*256;
    float tv = targ[i*DN + d];
    bool m = !(tv != tv);      // !isnan
    mk[k] = m ? 1.f : 0.f;
    c += mk[k];
    ycol[d*BN + i] = m ? tv : 0.f;
    xcol[d*BN + i] = pred[i*DN + d];
  }
  __shared__ float sh[4];
  __shared__ float logn_sh;
  float cw = wave_reduce_sum(c);
  if (lane == 0) sh[wave] = cw;
  __syncthreads();
  if (t == 0){
    float tot = sh[0] + sh[1] + sh[2] + sh[3];
    counts[d] = tot;
    logn_sh = logf(fmaxf(tot, 1.f));
  }
  __syncthreads();
  float ln = logn_sh;
  for (int k = 0; k < BN/256; k++){
    int i = t + k*256;
    logw[d*BN + i] = (mk[k] > 0.f) ? -ln : NEGW;
  }
}

// One Sinkhorn phase — r13 = exact revert to the proven r11 kernel (1042us,
// absmax 0.0). r12 post-mortem: persistent+grid-barrier costs ~45us/phase
// (LLC-round-trip atomics; launches are the cheap grid sync at ~3.4us), and
// the r12 staging rewrite added 1.6e7 bank conflicts. Model now closed:
// per-f2 issue cost = pk_fma(2cy) + pk_max(1.8) + 2x v_exp(~12.5) + pk_add(2)
// = 18.3cy vs measured 18.75 -> issue-bound at ~100% since r9; v_exp ~6cy
// is 67% of the budget. This structure is at its roofline.
__global__ __launch_bounds__(TPB) void sink_step(
      const float* __restrict__ xcol, const float* __restrict__ ycol,
      const float* __restrict__ logw,
      const float* __restrict__ dold, float* __restrict__ dnew,
      const float* __restrict__ Hold, float* __restrict__ Hnew,
      float eps, float inv_eps, float inv_eps_next, int mode){
  const float L2E = 1.44269504088896340736f;
  const float LN2 = 0.69314718055994530942f;
  __shared__ float4 pair4[JSPLIT*CPAD];   // ~16.25 KB planar: (y0,y1,h2_0,h2_1)
  __shared__ float2 pms[JSPLIT][RPB];     // 16 KB: per-chunk (max, sum)

  int bid = blockIdx.x;
  int rc  = bid & 15;          // 16 row-chunks of 128 rows
  int mat = (bid >> 4) & 3;    // 0:f 1:g 2:a 3:b
  int d   = bid >> 6;          // dim
  int t   = threadIdx.x;
  int rs  = t & (RS-1);        // row-slot
  int jc  = t >> 4;            // j-chunk 0..15

  const float* xb = xcol + d*BN;
  const float* yb = ycol + d*BN;
  const float* lw = logw + d*BN;
  const float* ri; const float* pj; int hsel;
  switch (mat){
    case 0:  ri = xb; pj = yb; hsel = 1; break;  // ft: rows x, pts y, dual g
    case 1:  ri = yb; pj = xb; hsel = 0; break;  // gt: rows y, pts x, dual f
    case 2:  ri = xb; pj = xb; hsel = 2; break;  // at
    default: ri = yb; pj = yb; hsel = 3; break;  // bt
  }
  const float* hp  = Hold + (size_t)hsel*DN*BN + d*BN;  // logw + dual/eps (prefused)
  const float* dmp = dold + (size_t)mat *DN*BN + d*BN;
  float*       op  = dnew + (size_t)mat *DN*BN + d*BN;
  float*       oh  = Hnew + (size_t)mat *DN*BN + d*BN;

  const float c1 = L2E * inv_eps;          // log2-domain 1/eps
  const float c2 = 0.5f * inv_eps * L2E;   // log2-domain 1/(2 eps)

  // ---- stage (y,y,h2,h2) planar for all 2048 j into LDS (padded chunks) ----
  const float2* pj2 = (const float2*)pj;
  const float2* h2src = (mode == 0) ? (const float2*)lw : (const float2*)hp;
  #pragma unroll
  for (int k = 0; k < SLOTS/TPB; k++){     // 4 iters
    int idx = t + k*TPB;
    int phys = idx + (idx >> 6);           // +1 pad slot per 64
    float2 y2 = pj2[idx];
    float2 hh = h2src[idx];
    pair4[phys] = make_float4(y2.x, y2.y,
                              fmaf(-c2*y2.x, y2.x, L2E*hh.x),
                              fmaf(-c2*y2.y, y2.y, L2E*hh.y));
  }

  int row0 = rc*RPB + rs;
  f2 a2[8];
  #pragma unroll
  for (int r = 0; r < 8; r++){
    float xi = ri[row0 + RS*r];
    float al = c1 * xi;
    a2[r] = (f2){al, al};
  }
  __syncthreads();

  // ---- single sweep: online max + exp-sum, 8-slot read batches ----
  const float4* cb = pair4 + jc*CPAD;      // this chunk's base
  float mrow[8];
  f2 sA[8], sB[8];
  #pragma unroll
  for (int r = 0; r < 8; r++){
    mrow[r] = -INFINITY;
    sA[r] = (f2){0.f, 0.f};
    sB[r] = (f2){0.f, 0.f};
  }
  #pragma unroll 1
  for (int q = 0; q < SPC; q += 8){
    float4 P0 = cb[q+0]; float4 P1 = cb[q+1];
    float4 P2 = cb[q+2]; float4 P3 = cb[q+3];
    float4 P4 = cb[q+4]; float4 P5 = cb[q+5];
    float4 P6 = cb[q+6]; float4 P7 = cb[q+7];
    #pragma unroll
    for (int r = 0; r < 8; r++){
      f2 a = a2[r];
      f2 v0 = __builtin_elementwise_fma(a, (f2){P0.x,P0.y}, (f2){P0.z,P0.w});
      f2 v1 = __builtin_elementwise_fma(a, (f2){P1.x,P1.y}, (f2){P1.z,P1.w});
      f2 v2 = __builtin_elementwise_fma(a, (f2){P2.x,P2.y}, (f2){P2.z,P2.w});
      f2 v3 = __builtin_elementwise_fma(a, (f2){P3.x,P3.y}, (f2){P3.z,P3.w});
      f2 v4 = __builtin_elementwise_fma(a, (f2){P4.x,P4.y}, (f2){P4.z,P4.w});
      f2 v5 = __builtin_elementwise_fma(a, (f2){P5.x,P5.y}, (f2){P5.z,P5.w});
      f2 v6 = __builtin_elementwise_fma(a, (f2){P6.x,P6.y}, (f2){P6.z,P6.w});
      f2 v7 = __builtin_elementwise_fma(a, (f2){P7.x,P7.y}, (f2){P7.z,P7.w});
      // batch max tree
      f2 t0 = __builtin_elementwise_max(v0, v1);
      f2 t1 = __builtin_elementwise_max(v2, v3);
      f2 t2 = __builtin_elementwise_max(v4, v5);
      f2 t3 = __builtin_elementwise_max(v6, v7);
      f2 u0 = __builtin_elementwise_max(t0, t1);
      f2 u1 = __builtin_elementwise_max(t2, t3);
      f2 w  = __builtin_elementwise_max(u0, u1);
      float bm = fmaxf(w.x, w.y);
      float mo = mrow[r];
      float mn = fmaxf(mo, bm);
      float sc = __builtin_amdgcn_exp2f(mo - mn);   // first batch: exp2(-inf)=0
      mrow[r] = mn;
      f2 scv = (f2){sc, sc};
      f2 mv  = (f2){mn, mn};
      f2 x0 = exp2_hw(v0 - mv);
      f2 x1 = exp2_hw(v1 - mv);
      f2 x2 = exp2_hw(v2 - mv);
      f2 x3 = exp2_hw(v3 - mv);
      f2 x4 = exp2_hw(v4 - mv);
      f2 x5 = exp2_hw(v5 - mv);
      f2 x6 = exp2_hw(v6 - mv);
      f2 x7 = exp2_hw(v7 - mv);
      // two accumulator chains, rescaled once per batch
      sA[r] = __builtin_elementwise_fma(sA[r], scv, x0);
      sB[r] = __builtin_elementwise_fma(sB[r], scv, x1);
      sA[r] += x2;  sB[r] += x3;
      sA[r] += x4;  sB[r] += x5;
      sA[r] += x6;  sB[r] += x7;
    }
  }
  #pragma unroll
  for (int r = 0; r < 8; r++){
    f2 s = sA[r] + sB[r];
    pms[jc][rs + RS*r] = make_float2(mrow[r], s.x + s.y);
  }
  __syncthreads();

  // ---- cross-chunk merge: M = max m_k; s = sum s_k * 2^(m_k - M) ----
  if (t < RPB){
    int row = rc*RPB + t;
    float M = -INFINITY;
    #pragma unroll
    for (int k = 0; k < JSPLIT; k++) M = fmaxf(M, pms[k][t].x);
    float s = 0.f;
    #pragma unroll
    for (int k = 0; k < JSPLIT; k++){
      float2 p = pms[k][t];
      s = fmaf(p.y, __builtin_amdgcn_exp2f(p.x - M), s);
    }
    float xi = ri[row];
    float beta = c2 * xi * xi;
    float lse2 = (M + __builtin_amdgcn_logf(s)) - beta;   // log2-domain LSE
    float tn = -eps * (LN2 * lse2);
    float outv;
    if (mode == 1 || (mode == 2 && mat >= 2)) outv = 0.5f * (dmp[row] + tn);
    else                                      outv = tn;
    op[row] = outv;
    oh[row] = fmaf(outv, inv_eps_next, lw[row]);  // prefused h for next step
  }
}

__global__ void reduce_kernel(const float* __restrict__ dual, const float* __restrict__ logw,
                              const float* __restrict__ counts, float* __restrict__ out){
  int d = blockIdx.x;
  int t = threadIdx.x;
  int lane = t & 63, wave = t >> 6;
  float acc = 0.f;
  for (int k = 0; k < BN/256; k++){
    int i = t + k*256;
    float w  = expf(logw[d*BN + i]);   // exp(-1e9) -> 0, else 1/n
    float fv = dual[0*DN*BN + d*BN + i];
    float gv = dual[1*DN*BN + d*BN + i];
    float av = dual[2*DN*BN + d*BN + i];
    float bv = dual[3*DN*BN + d*BN + i];
    acc += w * ((fv - av) + (gv - bv));
  }
  __shared__ float sh[4];
  float aw = wave_reduce_sum(acc);
  if (lane == 0) sh[wave] = aw;
  __syncthreads();
  if (t == 0){
    float tot = sh[0] + sh[1] + sh[2] + sh[3];
    out[1 + d] = (counts[d] > 1.5f) ? tot : 0.f;
  }
}

__global__ void total_kernel(float* __restrict__ out){
  if (threadIdx.x == 0 && blockIdx.x == 0){
    float s = 0.f;
    for (int d = 0; d < DN; d++) s += out[1 + d];
    out[0] = s / (float)DN;
  }
}

extern "C" void kernel_launch(void* const* d_in, const int* in_sizes, int n_in,
                              void* d_out, int out_size, void* d_ws, size_t ws_size,
                              hipStream_t stream){
  const float* pred = (const float*)d_in[0];
  const float* targ = (const float*)d_in[1];
  float* out = (float*)d_out;
  float* ws  = (float*)d_ws;

  float* xcol   = ws;
  float* ycol   = ws + (size_t)DN*BN;
  float* logw   = ws + (size_t)2*DN*BN;
  float* counts = ws + (size_t)3*DN*BN;
  float* buf0   = ws + (size_t)3*DN*BN + 64;
  float* buf1   = buf0 + (size_t)4*DN*BN;
  float* H0     = buf1 + (size_t)4*DN*BN;
  float* H1     = H0   + (size_t)4*DN*BN;

  // eps schedule (matches geomloss: diameter^p -> blur^p geometric, ratio scaling^p)
  float eps_list[64]; int n = 0;
  {
    const double P = 2.0, DIAM = 8.0, BLUR = 0.05, SC = 0.9;
    double ls = P*log(DIAM), le = P*log(BLUR), st = P*log(SC);
    eps_list[n++] = (float)pow(DIAM, P);                 // 64
    int cnt = (int)ceil((le - ls)/st);                   // 49
    for (int k = 0; k < cnt; k++) eps_list[n++] = (float)exp(ls + st*(double)k);
    eps_list[n++] = (float)(BLUR*BLUR);                  // 0.0025
  }

  setup_kernel<<<DN, 256, 0, stream>>>(pred, targ, xcol, ycol, logw, counts);

  dim3 grid(DN*4*16), blk(TPB);
  float* cur = buf0;  float* nxt = buf1;
  float* Hc  = H0;    float* Hn  = H1;
  {
    float e = eps_list[0];
    // mode 0: stage reads logw directly; writes cur + Hc (h for step 0's eps)
    sink_step<<<grid, blk, 0, stream>>>(xcol, ycol, logw, cur, cur, Hc, Hc,
                                        e, 1.f/e, 1.f/eps_list[0], 0);
  }
  for (int k = 0; k < n; k++){
    float e = eps_list[k];
    float en = (k+1 < n) ? eps_list[k+1] : eps_list[n-1]; // final extrap uses last eps
    sink_step<<<grid, blk, 0, stream>>>(xcol, ycol, logw, cur, nxt, Hc, Hn,
                                        e, 1.f/e, 1.f/en, 1);
    float* tb = cur; cur = nxt; nxt = tb;
    float* th = Hc;  Hc  = Hn;  Hn  = th;
  }
  {
    float e = eps_list[n-1];
    sink_step<<<grid, blk, 0, stream>>>(xcol, ycol, logw, cur, nxt, Hc, Hn,
                                        e, 1.f/e, 1.f/e, 2);
    float* tb = cur; cur = nxt; nxt = tb;
    float* th = Hc;  Hc  = Hn;  Hn  = th;
  }
  reduce_kernel<<<DN, 256, 0, stream>>>(cur, logw, counts, out);
  total_kernel<<<1, 64, 0, stream>>>(out);
}